// Round 2
// baseline (2065.157 us; speedup 1.0000x reference)
//
#include <hip/hip_runtime.h>

// ---------------------------------------------------------------------------
// RPN forward, MI355X. Only batch element 7 contributes to the output.
// Pipeline: conv3x3+leaky -> 1x1 heads -> decode/score/key -> O(N^2) rank
// sort -> top-6000 -> NMS bitmask (reference's yy2=max bug replicated) ->
// serial scan (early exit at 300 kept) -> 300x4 boxes.
// All arithmetic fp32 FMA, deterministic order, precise division.
// ---------------------------------------------------------------------------

#define NPIX 2500      // 50*50
#define NANCH 22500    // 2500*9
#define NKEY 22528     // NANCH padded to 88*256 (sentinel tail)
#define PRE 6000
#define MASKW 94       // ceil(6000/64) usable words
#define MW 96          // storage stride in words (4 chunks * 24)
#define JCHUNK 1536    // j-chunk for mask kernel (24 words)

// ---------------- conv 3x3, 512->512, pad 1, + bias + leaky ----------------
// grid (16 ocGroups, 40 pixel tiles), block 128 (2 waves). Wave handles 16 oc.
// Pixel tile = 64 linear pixels (row-major over 50x50); a tile can span up to
// THREE output rows (start col >= 37), so FIVE input rows are staged.
// cin chunked by 32 into LDS (32 * 5 rows * 52 cols = 33.3 KB).
__global__ __launch_bounds__(128) void conv3x3_leaky(
    const float* __restrict__ x,    // batch-7 base (512,50,50)
    const float* __restrict__ wt,   // (512,512,3,3)
    const float* __restrict__ bias, // (512)
    float* __restrict__ feat)       // (512,50,50)
{
    __shared__ float sIn[32 * 260];              // 5 rows * 52 cols per cin
    const int tid  = threadIdx.x;
    const int lane = tid & 63;
    const int wq   = tid >> 6;                   // 0..1
    const int tile = blockIdx.y;                 // 0..39
    const int ocb  = blockIdx.x * 32 + wq * 16;  // wave's first oc

    int p = tile * 64 + lane;
    const bool active = (p < NPIX);
    if (!active) p = NPIX - 1;
    const int hh = p / 50;
    const int ww = p - hh * 50;
    const int h0 = (tile * 64) / 50;
    const int rbase = (hh - h0) * 52 + ww;       // LDS read base (row off 0..2)

    float acc[16];
    #pragma unroll
    for (int o = 0; o < 16; ++o) acc[o] = 0.f;

    for (int cc = 0; cc < 16; ++cc) {            // 16 chunks of 32 cin
        __syncthreads();
        // stage 32 cin x 5 rows x 52 cols; 320 units of 26 cols
        for (int u = tid; u < 320; u += 128) {
            const int cinl = u / 10;
            const int rem  = u - cinl * 10;
            const int row  = rem >> 1;           // 0..4 -> img row h0-1+row
            const int col0 = (rem & 1) * 26;
            const int gr   = h0 - 1 + row;
            const bool rok = (gr >= 0) && (gr < 50);
            float* dst = &sIn[cinl * 260 + row * 52 + col0];
            const float* src = x + (size_t)(cc * 32 + cinl) * NPIX + gr * 50;
            #pragma unroll
            for (int q = 0; q < 26; ++q) {
                const int gc = col0 + q - 1;     // storage col = img col + 1
                float v = 0.f;
                if (rok && gc >= 0 && gc < 50) v = src[gc];
                dst[q] = v;
            }
        }
        __syncthreads();

        for (int cinl = 0; cinl < 32; ++cinl) {
            float v[9];
            const float* s0 = &sIn[cinl * 260 + rbase];
            #pragma unroll
            for (int r = 0; r < 3; ++r)
                #pragma unroll
                for (int s = 0; s < 3; ++s)
                    v[r * 3 + s] = s0[r * 52 + s];
            const int cin = cc * 32 + cinl;
            const float* wp = wt + (size_t)cin * 9;
            #pragma unroll
            for (int o = 0; o < 16; ++o) {
                const float* w = wp + (size_t)(ocb + o) * 4608;  // uniform -> s_load
                #pragma unroll
                for (int t = 0; t < 9; ++t)
                    acc[o] = fmaf(w[t], v[t], acc[o]);
            }
        }
    }

    if (active) {
        #pragma unroll
        for (int o = 0; o < 16; ++o) {
            float r = acc[o] + bias[ocb + o];
            r = (r >= 0.f) ? r : 0.01f * r;
            feat[(size_t)(ocb + o) * NPIX + p] = r;
        }
    }
}

// ---------------- 1x1 heads: reg (36) + cls (18), stored oc-major ----------
// grid (20 pixel tiles of 125, 3 oc-chunks of 18), block 128.
__global__ __launch_bounds__(128) void conv1x1_heads(
    const float* __restrict__ feat,
    const float* __restrict__ rw, const float* __restrict__ rb,
    const float* __restrict__ cw, const float* __restrict__ cb,
    float* __restrict__ regcls)   // (54, 2500)
{
    const int tid  = threadIdx.x;
    const int pix0 = blockIdx.x * 125 + tid;
    const bool act = (tid < 125);
    const int pix  = act ? pix0 : (NPIX - 1);
    const int chunk = blockIdx.y;
    const float* wb; const float* bb; int ocbase;
    if (chunk == 0)      { wb = rw;            bb = rb;      ocbase = 0;  }
    else if (chunk == 1) { wb = rw + 18 * 512; bb = rb + 18; ocbase = 18; }
    else                 { wb = cw;            bb = cb;      ocbase = 36; }

    float acc[18];
    #pragma unroll
    for (int k = 0; k < 18; ++k) acc[k] = 0.f;

    for (int cin = 0; cin < 512; ++cin) {
        const float v = feat[(size_t)cin * NPIX + pix];
        #pragma unroll
        for (int k = 0; k < 18; ++k)
            acc[k] = fmaf(wb[k * 512 + cin], v, acc[k]);
    }
    if (act) {
        #pragma unroll
        for (int k = 0; k < 18; ++k)
            regcls[(size_t)(ocbase + k) * NPIX + pix] = acc[k] + bb[k];
    }
}

// ---------------- decode: anchors, softmax score, sortable key -------------
__global__ __launch_bounds__(256) void decodeK(
    const float* __restrict__ regcls,
    float4* __restrict__ boxes,
    unsigned long long* __restrict__ keys)
{
    const int i = blockIdx.x * 256 + threadIdx.x;
    if (i >= NANCH) {
        if (i < NKEY) keys[i] = 0xFFFFFFFFFFFFFFFFull;  // sentinel: > all keys
        return;
    }
    const int pos = i / 9;
    const int a   = i - pos * 9;
    const int hh  = pos / 50;
    const int wwp = pos - hh * 50;
    const int r = a / 3, s = a - r * 3;

    const float base_s[3] = {128.f, 256.f, 512.f};
    const float sq [3] = {0.70710678118654752440f, 1.0f, 1.41421356237309504880f};
    const float sqi[3] = {1.41421356237309504880f, 1.0f, 0.70710678118654752440f};
    const float hs = base_s[s] * sq[r];
    const float ws = base_s[s] * sqi[r];
    const float cx = (float)(hh * 16 + 8);    // cx indexed by h (reference quirk)
    const float cy = (float)(wwp * 16 + 8);
    const float ax = cx - ws * 0.5f;
    const float ay = cy - hs * 0.5f;

    const float pr0 = regcls[(size_t)(a * 4 + 0) * NPIX + pos];
    const float pr1 = regcls[(size_t)(a * 4 + 1) * NPIX + pos];
    const float pr2 = regcls[(size_t)(a * 4 + 2) * NPIX + pos];
    const float pr3 = regcls[(size_t)(a * 4 + 3) * NPIX + pos];
    const float c0  = regcls[(size_t)(36 + a * 2 + 0) * NPIX + pos];
    const float c1  = regcls[(size_t)(36 + a * 2 + 1) * NPIX + pos];

    // softmax over 2 classes: exp(x - max) / sum — matches jax.nn.softmax
    const float m  = fmaxf(c0, c1);
    const float e0 = expf(c0 - m);
    const float e1 = expf(c1 - m);
    const float score = e1 / (e0 + e1);

    const float t0 = pr0 + ax;
    const float t1 = pr1 + ay;
    const float hi = 799.0f;
    const float rx1 = fminf(fmaxf(t0, 0.f), hi);
    const float ry1 = fminf(fmaxf(t1, 0.f), hi);
    const float rx2 = fminf(fmaxf((t0 + pr2) + ws, 0.f), hi);
    const float ry2 = fminf(fmaxf((t1 + pr3) + hs, 0.f), hi);
    const float bw = pr2 + ws;
    const float bh = pr3 + hs;
    const bool valid = (bw >= 16.f) && (bh >= 16.f);
    const float sc = valid ? score : -__builtin_inff();

    unsigned u = __float_as_uint(sc);
    u = (u & 0x80000000u) ? ~u : (u | 0x80000000u);  // monotone ascending map
    const unsigned k32 = ~u;                          // descending score
    keys[i]  = ((unsigned long long)k32 << 32) | (unsigned)i;  // tie: asc index
    boxes[i] = make_float4(rx1, ry1, rx2, ry2);
}

// ---------------- O(N^2) rank (stable argsort position) --------------------
// grid (88 i-blocks, 8 j-chunks of 2816). rank[i] = #{j : key_j < key_i}.
// j-address is wave-uniform -> scalar loads (s_load), compare+count in VALU.
__global__ __launch_bounds__(256) void rankK(
    const unsigned long long* __restrict__ keys, int* __restrict__ rank)
{
    const int i = blockIdx.x * 256 + threadIdx.x;
    const unsigned long long my = (i < NANCH) ? keys[i] : 0ull;
    const unsigned long long* kj = keys + blockIdx.y * 2816;
    int cnt = 0;
    for (int t = 0; t < 2816; t += 8) {
        #pragma unroll
        for (int q = 0; q < 8; ++q)
            cnt += (kj[t + q] < my) ? 1 : 0;
    }
    if (i < NANCH) atomicAdd(&rank[i], cnt);
}

__global__ __launch_bounds__(256) void scatterK(
    const float4* __restrict__ boxes, const int* __restrict__ rank,
    float4* __restrict__ sboxes)
{
    const int i = blockIdx.x * 256 + threadIdx.x;
    if (i < NANCH) {
        const int r = rank[i];
        if (r < PRE) sboxes[r] = boxes[i];
    }
}

// ---------------- NMS suppression bitmask (reference bug replicated) -------
// grid (375 row-tiles of 16, 4 j-chunks of 1536=24 words), block 256.
__global__ __launch_bounds__(256) void nmsMaskK(
    const float4* __restrict__ sb, unsigned long long* __restrict__ mask)
{
    __shared__ float sx1[JCHUNK], sy1[JCHUNK], sx2[JCHUNK], sy2[JCHUNK], sar[JCHUNK];
    const int tid = threadIdx.x;
    const int jbase = blockIdx.y * JCHUNK;
    for (int t = tid; t < JCHUNK; t += 256) {
        const int j = jbase + t;
        if (j < PRE) {
            const float4 b = sb[j];
            sx1[t] = b.x; sy1[t] = b.y; sx2[t] = b.z; sy2[t] = b.w;
            sar[t] = (b.z - b.x + 1.f) * (b.w - b.y + 1.f);
        } else {
            sx1[t] = 0.f; sy1[t] = 0.f; sx2[t] = -1.f; sy2[t] = 0.f; sar[t] = 0.f;
        }
    }
    __syncthreads();
    const int i = blockIdx.x * 16 + (tid >> 4);
    const float4 bi = sb[i];
    const float x1 = bi.x, y1 = bi.y, x2 = bi.z, y2 = bi.w;
    const float ar = (x2 - x1 + 1.f) * (y2 - y1 + 1.f);
    for (int w = (tid & 15); w < 24; w += 16) {
        unsigned long long bits = 0ull;
        const int l0 = w * 64;
        for (int u = 0; u < 64; ++u) {
            const int j = jbase + l0 + u;
            if (j > i && j < PRE) {
                const int l = l0 + u;
                const float xx1 = fmaxf(x1, sx1[l]);
                const float yy1 = fmaxf(y1, sy1[l]);
                const float xx2 = fminf(x2, sx2[l]);
                const float yy2 = fmaxf(y2, sy2[l]);        // reference bug: max
                const float wv = fmaxf(0.f, xx2 - xx1 + 1.f);
                const float hv = fmaxf(0.f, yy2 - yy1 + 1.f);
                const float inter = wv * hv;
                const float ov = inter / ((ar + sar[l]) - inter);  // precise div
                if (ov > 0.7f) bits |= (1ull << u);
            }
        }
        mask[(size_t)i * MW + blockIdx.y * 24 + w] = bits;
    }
}

// ---------------- serial NMS scan + output (single block) ------------------
// Batches of 32 rows, double-buffered LDS staging by waves 1-3; wave 0 scans.
// Early exit once 300 boxes kept. Fuses final 300x4 output write.
#define SB 32
__global__ __launch_bounds__(256) void nmsScanOutK(
    const unsigned long long* __restrict__ mask,
    const float4* __restrict__ sb,
    float* __restrict__ out)
{
    __shared__ unsigned long long sBuf[2][SB][MW];   // 48 KB
    __shared__ unsigned long long sRem[MW];
    __shared__ unsigned long long sKeep[MW];
    __shared__ int sKept[300];
    __shared__ int sCnt;
    __shared__ int sDone;
    const int tid = threadIdx.x;
    if (tid < MW) { sRem[tid] = 0ull; sKeep[tid] = 0ull; }
    if (tid == 0) { sCnt = 0; sDone = 0; }
    // preload batch 0
    if (tid >= 64) {
        const int lt = tid - 64;
        for (int k = 0; k < 16; ++k) {
            const int idx = lt + k * 192;            // 0..3071 = 32*96
            const int row = idx / MW;
            const int w   = idx - row * MW;
            sBuf[0][row][w] = mask[(size_t)row * MW + w];
        }
    }
    __syncthreads();

    int cnt = 0;
    for (int t = 0; t < 188; ++t) {
        if (tid >= 64 && (t + 1) < 188) {            // loaders: batch t+1
            const int lt = tid - 64;
            const int rbase = (t + 1) * SB;
            for (int k = 0; k < 16; ++k) {
                const int idx = lt + k * 192;
                const int row = idx / MW;
                const int w   = idx - row * MW;
                const int gi  = rbase + row;
                if (gi < PRE) sBuf[(t + 1) & 1][row][w] = mask[(size_t)gi * MW + w];
            }
        }
        if (tid < 64) {                              // scanner wave
            const int lane = tid;
            const int base = t * SB;
            const int w0 = base >> 6;
            const int sh = base & 63;                // 0 or 32
            unsigned long long cur = sRem[w0];
            unsigned long long kb = 0ull;
            for (int k = 0; k < SB; ++k) {
                const int i = base + k;
                if (i >= PRE) break;
                if (!((cur >> (sh + k)) & 1ull)) {
                    if (lane == 0 && cnt < 300) sKept[cnt] = i;
                    ++cnt;
                    kb |= (1ull << k);
                    if (cnt >= 300) break;
                    cur |= sBuf[t & 1][k][w0];
                    for (int w = lane; w < MASKW; w += 64)
                        if (w > w0) sRem[w] |= sBuf[t & 1][k][w];
                }
            }
            if (lane == 0) {
                sRem[w0] = cur;
                sKeep[w0] |= (kb << sh);
                sCnt = cnt;
                if (cnt >= 300) sDone = 1;
            }
        }
        __syncthreads();
        const int done = sDone;
        __syncthreads();
        if (done) break;
    }

    if (tid == 0 && sCnt < 300) {                    // filler: unkept, asc index
        int c = sCnt;
        for (int i = 0; i < PRE && c < 300; ++i)
            if (!((sKeep[i >> 6] >> (i & 63)) & 1ull)) sKept[c++] = i;
    }
    __syncthreads();
    for (int s = tid; s < 300; s += 256) {
        const float4 b = sb[sKept[s]];
        out[s * 4 + 0] = b.x;
        out[s * 4 + 1] = b.y;
        out[s * 4 + 2] = b.z - b.x + 1.0f;
        out[s * 4 + 3] = b.w - b.y + 1.0f;
    }
}

// ---------------------------------------------------------------------------
extern "C" void kernel_launch(void* const* d_in, const int* in_sizes, int n_in,
                              void* d_out, int out_size, void* d_ws, size_t ws_size,
                              hipStream_t stream)
{
    (void)in_sizes; (void)n_in; (void)out_size; (void)ws_size;
    const float* x   = (const float*)d_in[0] + (size_t)7 * 512 * NPIX; // batch 7
    const float* cw3 = (const float*)d_in[1];
    const float* cb3 = (const float*)d_in[2];
    const float* rw  = (const float*)d_in[3];
    const float* rb  = (const float*)d_in[4];
    const float* clw = (const float*)d_in[5];
    const float* clb = (const float*)d_in[6];
    float* out = (float*)d_out;

    char* p = (char*)d_ws;
    auto alloc = [&](size_t n) { char* r = p; p += (n + 255) & ~(size_t)255; return r; };
    float*  feat   = (float*)alloc((size_t)512 * NPIX * 4);       // 5.12 MB
    float*  regcls = (float*)alloc((size_t)54 * NPIX * 4);        // 0.54 MB
    float4* boxes  = (float4*)alloc((size_t)NANCH * 16);          // 0.36 MB
    unsigned long long* keys = (unsigned long long*)alloc((size_t)NKEY * 8);
    int*    rank   = (int*)alloc((size_t)NANCH * 4);
    float4* sboxes = (float4*)alloc((size_t)PRE * 16);
    unsigned long long* mask = (unsigned long long*)alloc((size_t)PRE * MW * 8); // 4.6 MB

    hipMemsetAsync(rank, 0, (size_t)NANCH * 4, stream);
    conv3x3_leaky <<<dim3(16, 40), 128, 0, stream>>>(x, cw3, cb3, feat);
    conv1x1_heads <<<dim3(20, 3), 128, 0, stream>>>(feat, rw, rb, clw, clb, regcls);
    decodeK       <<<88, 256, 0, stream>>>(regcls, boxes, keys);
    rankK         <<<dim3(88, 8), 256, 0, stream>>>(keys, rank);
    scatterK      <<<88, 256, 0, stream>>>(boxes, rank, sboxes);
    nmsMaskK      <<<dim3(375, 4), 256, 0, stream>>>(sboxes, mask);
    nmsScanOutK   <<<1, 256, 0, stream>>>(mask, sboxes, out);
}

// Round 3
// 1580.475 us; speedup vs baseline: 1.3067x; 1.3067x over previous
//
#include <hip/hip_runtime.h>

// ---------------------------------------------------------------------------
// RPN forward, MI355X. Only batch element 7 contributes to the output.
// conv3x3 (cin-split partials, no LDS) -> reduce+leaky -> 1x1 heads ->
// decode/score/key -> O(N^2) rank sort -> top-6000 -> NMS bitmask
// (reference's yy2=max bug replicated) -> register-resident serial scan ->
// 300x4 boxes. Deterministic fp32 everywhere (no float atomics).
// ---------------------------------------------------------------------------

#define NPIX 2500      // 50*50
#define NANCH 22500    // 2500*9
#define NKEY 22528     // NANCH padded to 88*256 (sentinel tail)
#define PRE 6000
#define MASKW 94       // ceil(6000/64) usable words
#define MW 96          // storage stride in words
#define JCHUNK 1536    // j-chunk for mask kernel (24 words)
#define CS 4           // cin splits for conv3x3
#define CGRP 128       // cin per split

// ---------------- conv 3x3 partials: no LDS, lane=pixel, wave=16 oc --------
// grid (32 ocGroups, 40 pixel tiles, 4 cin groups), block 64 (1 wave).
// Input reads are lane-coalesced globals (L1-cached, 3-row window reuse);
// weights are wave-uniform scalar loads. 20 waves/CU for latency hiding.
__global__ __launch_bounds__(64, 5) void conv3x3_part(
    const float* __restrict__ x,    // batch-7 base (512,50,50)
    const float* __restrict__ wt,   // (512,512,3,3)
    float* __restrict__ part)       // (CS,512,2500)
{
    const int lane = threadIdx.x;
    const int tile = blockIdx.y;
    const int ocb  = blockIdx.x * 16;
    const int cing = blockIdx.z * CGRP;

    int p = tile * 64 + lane;
    const bool active = (p < NPIX);
    if (!active) p = NPIX - 1;
    const int hh = p / 50;
    const int ww = p - hh * 50;

    // 9 tap offsets, clamped-safe + float mask
    int   soff[9];
    float mk[9];
    #pragma unroll
    for (int r = 0; r < 3; ++r) {
        #pragma unroll
        for (int c = 0; c < 3; ++c) {
            const int gr = hh + r - 1, gc = ww + c - 1;
            const bool ok = (gr >= 0) & (gr < 50) & (gc >= 0) & (gc < 50);
            soff[r * 3 + c] = ok ? (gr * 50 + gc) : 0;
            mk[r * 3 + c]   = ok ? 1.0f : 0.0f;
        }
    }

    float acc[16];
    #pragma unroll
    for (int o = 0; o < 16; ++o) acc[o] = 0.f;

    for (int cin = 0; cin < CGRP; ++cin) {
        const float* xp = x + (size_t)(cing + cin) * NPIX;
        float v[9];
        #pragma unroll
        for (int k = 0; k < 9; ++k)
            v[k] = xp[soff[k]] * mk[k];
        const float* wbase = wt + ((size_t)ocb * 512 + (cing + cin)) * 9;
        #pragma unroll
        for (int o = 0; o < 16; ++o) {
            const float* w = wbase + (size_t)o * 4608;  // wave-uniform -> s_load
            #pragma unroll
            for (int t = 0; t < 9; ++t)
                acc[o] = fmaf(w[t], v[t], acc[o]);
        }
    }

    if (active) {
        float* dst = part + ((size_t)blockIdx.z * 512 + ocb) * NPIX + p;
        #pragma unroll
        for (int o = 0; o < 16; ++o)
            dst[(size_t)o * NPIX] = acc[o];
    }
}

// ---------------- reduce partials + bias + leaky ---------------------------
__global__ __launch_bounds__(256) void reduce_leaky(
    const float* __restrict__ part, const float* __restrict__ bias,
    float* __restrict__ feat)
{
    const int i = blockIdx.x * 256 + threadIdx.x;
    if (i >= 512 * NPIX) return;
    const int oc = i / NPIX;
    float s = part[i];
    s += part[(size_t)1 * 512 * NPIX + i];
    s += part[(size_t)2 * 512 * NPIX + i];
    s += part[(size_t)3 * 512 * NPIX + i];
    s += bias[oc];
    s = (s >= 0.f) ? s : 0.01f * s;
    feat[i] = s;
}

// ---------------- 1x1 heads: reg (36) + cls (18), stored oc-major ----------
// grid (40 pixel tiles of 64, 3 oc-chunks of 18), block 64.
__global__ __launch_bounds__(64) void conv1x1_heads(
    const float* __restrict__ feat,
    const float* __restrict__ rw, const float* __restrict__ rb,
    const float* __restrict__ cw, const float* __restrict__ cb,
    float* __restrict__ regcls)   // (54, 2500)
{
    const int tid  = threadIdx.x;
    const int pix0 = blockIdx.x * 64 + tid;
    const bool act = (pix0 < NPIX);
    const int pix  = act ? pix0 : (NPIX - 1);
    const int chunk = blockIdx.y;
    const float* wb; const float* bb; int ocbase;
    if (chunk == 0)      { wb = rw;            bb = rb;      ocbase = 0;  }
    else if (chunk == 1) { wb = rw + 18 * 512; bb = rb + 18; ocbase = 18; }
    else                 { wb = cw;            bb = cb;      ocbase = 36; }

    float acc[18];
    #pragma unroll
    for (int k = 0; k < 18; ++k) acc[k] = 0.f;

    for (int cin = 0; cin < 512; ++cin) {
        const float v = feat[(size_t)cin * NPIX + pix];
        #pragma unroll
        for (int k = 0; k < 18; ++k)
            acc[k] = fmaf(wb[k * 512 + cin], v, acc[k]);
    }
    if (act) {
        #pragma unroll
        for (int k = 0; k < 18; ++k)
            regcls[(size_t)(ocbase + k) * NPIX + pix] = acc[k] + bb[k];
    }
}

// ---------------- decode: anchors, softmax score, sortable key -------------
__global__ __launch_bounds__(256) void decodeK(
    const float* __restrict__ regcls,
    float4* __restrict__ boxes,
    unsigned long long* __restrict__ keys)
{
    const int i = blockIdx.x * 256 + threadIdx.x;
    if (i >= NANCH) {
        if (i < NKEY) keys[i] = 0xFFFFFFFFFFFFFFFFull;  // sentinel: > all keys
        return;
    }
    const int pos = i / 9;
    const int a   = i - pos * 9;
    const int hh  = pos / 50;
    const int wwp = pos - hh * 50;
    const int r = a / 3, s = a - r * 3;

    const float base_s[3] = {128.f, 256.f, 512.f};
    const float sq [3] = {0.70710678118654752440f, 1.0f, 1.41421356237309504880f};
    const float sqi[3] = {1.41421356237309504880f, 1.0f, 0.70710678118654752440f};
    const float hs = base_s[s] * sq[r];
    const float ws = base_s[s] * sqi[r];
    const float cx = (float)(hh * 16 + 8);    // cx indexed by h (reference quirk)
    const float cy = (float)(wwp * 16 + 8);
    const float ax = cx - ws * 0.5f;
    const float ay = cy - hs * 0.5f;

    const float pr0 = regcls[(size_t)(a * 4 + 0) * NPIX + pos];
    const float pr1 = regcls[(size_t)(a * 4 + 1) * NPIX + pos];
    const float pr2 = regcls[(size_t)(a * 4 + 2) * NPIX + pos];
    const float pr3 = regcls[(size_t)(a * 4 + 3) * NPIX + pos];
    const float c0  = regcls[(size_t)(36 + a * 2 + 0) * NPIX + pos];
    const float c1  = regcls[(size_t)(36 + a * 2 + 1) * NPIX + pos];

    // softmax over 2 classes: exp(x - max) / sum — matches jax.nn.softmax
    const float m  = fmaxf(c0, c1);
    const float e0 = expf(c0 - m);
    const float e1 = expf(c1 - m);
    const float score = e1 / (e0 + e1);

    const float t0 = pr0 + ax;
    const float t1 = pr1 + ay;
    const float hi = 799.0f;
    const float rx1 = fminf(fmaxf(t0, 0.f), hi);
    const float ry1 = fminf(fmaxf(t1, 0.f), hi);
    const float rx2 = fminf(fmaxf((t0 + pr2) + ws, 0.f), hi);
    const float ry2 = fminf(fmaxf((t1 + pr3) + hs, 0.f), hi);
    const float bw = pr2 + ws;
    const float bh = pr3 + hs;
    const bool valid = (bw >= 16.f) && (bh >= 16.f);
    const float sc = valid ? score : -__builtin_inff();

    unsigned u = __float_as_uint(sc);
    u = (u & 0x80000000u) ? ~u : (u | 0x80000000u);  // monotone ascending map
    const unsigned k32 = ~u;                          // descending score
    keys[i]  = ((unsigned long long)k32 << 32) | (unsigned)i;  // tie: asc index
    boxes[i] = make_float4(rx1, ry1, rx2, ry2);
}

// ---------------- O(N^2) rank (stable argsort position) --------------------
__global__ __launch_bounds__(256) void rankK(
    const unsigned long long* __restrict__ keys, int* __restrict__ rank)
{
    const int i = blockIdx.x * 256 + threadIdx.x;
    const unsigned long long my = (i < NANCH) ? keys[i] : 0ull;
    const unsigned long long* kj = keys + blockIdx.y * 2816;
    int cnt = 0;
    for (int t = 0; t < 2816; t += 8) {
        #pragma unroll
        for (int q = 0; q < 8; ++q)
            cnt += (kj[t + q] < my) ? 1 : 0;
    }
    if (i < NANCH) atomicAdd(&rank[i], cnt);
}

__global__ __launch_bounds__(256) void scatterK(
    const float4* __restrict__ boxes, const int* __restrict__ rank,
    float4* __restrict__ sboxes)
{
    const int i = blockIdx.x * 256 + threadIdx.x;
    if (i < NANCH) {
        const int r = rank[i];
        if (r < PRE) sboxes[r] = boxes[i];
    }
}

// ---------------- NMS suppression bitmask (reference bug replicated) -------
__global__ __launch_bounds__(256) void nmsMaskK(
    const float4* __restrict__ sb, unsigned long long* __restrict__ mask)
{
    __shared__ float sx1[JCHUNK], sy1[JCHUNK], sx2[JCHUNK], sy2[JCHUNK], sar[JCHUNK];
    const int tid = threadIdx.x;
    const int jbase = blockIdx.y * JCHUNK;
    for (int t = tid; t < JCHUNK; t += 256) {
        const int j = jbase + t;
        if (j < PRE) {
            const float4 b = sb[j];
            sx1[t] = b.x; sy1[t] = b.y; sx2[t] = b.z; sy2[t] = b.w;
            sar[t] = (b.z - b.x + 1.f) * (b.w - b.y + 1.f);
        } else {
            sx1[t] = 0.f; sy1[t] = 0.f; sx2[t] = -1.f; sy2[t] = 0.f; sar[t] = 0.f;
        }
    }
    __syncthreads();
    const int i = blockIdx.x * 16 + (tid >> 4);
    const float4 bi = sb[i];
    const float x1 = bi.x, y1 = bi.y, x2 = bi.z, y2 = bi.w;
    const float ar = (x2 - x1 + 1.f) * (y2 - y1 + 1.f);
    for (int w = (tid & 15); w < 24; w += 16) {
        unsigned long long bits = 0ull;
        const int l0 = w * 64;
        for (int u = 0; u < 64; ++u) {
            const int j = jbase + l0 + u;
            if (j > i && j < PRE) {
                const int l = l0 + u;
                const float xx1 = fmaxf(x1, sx1[l]);
                const float yy1 = fmaxf(y1, sy1[l]);
                const float xx2 = fminf(x2, sx2[l]);
                const float yy2 = fmaxf(y2, sy2[l]);        // reference bug: max
                const float wv = fmaxf(0.f, xx2 - xx1 + 1.f);
                const float hv = fmaxf(0.f, yy2 - yy1 + 1.f);
                const float inter = wv * hv;
                const float ov = inter / ((ar + sar[l]) - inter);  // precise div
                if (ov > 0.7f) bits |= (1ull << u);
            }
        }
        mask[(size_t)i * MW + blockIdx.y * 24 + w] = bits;
    }
}

// ---------------- serial NMS scan + output (single block) ------------------
// Wave 0 scans with remv mask in REGISTERS (lane l holds words l and 64+l);
// bit tests via readlane, per-kept update = 2 ds_reads + ORs. Waves 1-3
// double-buffer-stage mask rows into LDS with 16B loads.
#define SB 32
__global__ __launch_bounds__(256) void nmsScanOutK(
    const unsigned long long* __restrict__ mask,
    const float4* __restrict__ sb,
    float* __restrict__ out)
{
    __shared__ unsigned long long sBuf[2][SB][MW];   // 48 KB
    __shared__ unsigned long long sKeep[MASKW];
    __shared__ int sKept[300];
    __shared__ int sCnt;
    __shared__ int sDone;
    const int tid = threadIdx.x;
    if (tid < MASKW) sKeep[tid] = 0ull;
    if (tid == 0) { sCnt = 0; sDone = 0; }
    // preload batch 0 (16B vector loads; mask rows are 16B-aligned, 768B)
    if (tid >= 64) {
        const int lt = tid - 64;
        const ulonglong2* src = (const ulonglong2*)mask;
        ulonglong2* dst = (ulonglong2*)&sBuf[0][0][0];
        for (int k = 0; k < 8; ++k) {
            const int idx2 = lt + k * 192;           // 0..1535 = 32*48
            dst[idx2] = src[idx2];
        }
    }
    __syncthreads();

    unsigned long long rem0 = 0ull, rem1 = 0ull;     // lane l: words l, 64+l
    int cnt = 0;
    for (int t = 0; t < 188; ++t) {
        if (tid >= 64 && (t + 1) < 188) {            // loaders: batch t+1
            const int lt = tid - 64;
            const int rbase = (t + 1) * SB;
            const ulonglong2* src = (const ulonglong2*)(mask + (size_t)rbase * MW);
            ulonglong2* dst = (ulonglong2*)&sBuf[(t + 1) & 1][0][0];
            for (int k = 0; k < 8; ++k) {
                const int idx2 = lt + k * 192;
                const int row = idx2 / 48;
                if (rbase + row < PRE) dst[idx2] = src[idx2];
            }
        }
        if (tid < 64) {                              // scanner wave
            const int l = tid;
            const int base = t * SB;
            unsigned long long kb = 0ull;
            #pragma unroll 1
            for (int k = 0; k < SB; ++k) {
                const int i = base + k;
                if (i >= PRE) break;
                const int w = i >> 6;
                const int b = i & 63;
                unsigned sel;
                if (w < 64) {
                    sel = (b < 32) ? __builtin_amdgcn_readlane((unsigned)rem0, w)
                                   : __builtin_amdgcn_readlane((unsigned)(rem0 >> 32), w);
                } else {
                    sel = (b < 32) ? __builtin_amdgcn_readlane((unsigned)rem1, w - 64)
                                   : __builtin_amdgcn_readlane((unsigned)(rem1 >> 32), w - 64);
                }
                if (!((sel >> (b & 31)) & 1u)) {
                    if (l == 0 && cnt < 300) sKept[cnt] = i;
                    ++cnt;
                    kb |= (1ull << k);
                    if (cnt >= 300) break;
                    const unsigned long long m0 = sBuf[t & 1][k][l];
                    const unsigned long long m1 = (l < 30) ? sBuf[t & 1][k][64 + l] : 0ull;
                    rem0 |= m0;
                    rem1 |= m1;
                }
            }
            if (l == 0) {
                sKeep[base >> 6] |= (kb << (base & 63));
                sCnt = cnt;
                if (cnt >= 300) sDone = 1;
            }
        }
        __syncthreads();
        const int done = sDone;
        __syncthreads();
        if (done) break;
    }

    if (tid == 0 && sCnt < 300) {                    // filler: unkept, asc index
        int c = sCnt;
        for (int i = 0; i < PRE && c < 300; ++i)
            if (!((sKeep[i >> 6] >> (i & 63)) & 1ull)) sKept[c++] = i;
    }
    __syncthreads();
    for (int s = tid; s < 300; s += 256) {
        const float4 b = sb[sKept[s]];
        out[s * 4 + 0] = b.x;
        out[s * 4 + 1] = b.y;
        out[s * 4 + 2] = b.z - b.x + 1.0f;
        out[s * 4 + 3] = b.w - b.y + 1.0f;
    }
}

// ---------------------------------------------------------------------------
extern "C" void kernel_launch(void* const* d_in, const int* in_sizes, int n_in,
                              void* d_out, int out_size, void* d_ws, size_t ws_size,
                              hipStream_t stream)
{
    (void)in_sizes; (void)n_in; (void)out_size; (void)ws_size;
    const float* x   = (const float*)d_in[0] + (size_t)7 * 512 * NPIX; // batch 7
    const float* cw3 = (const float*)d_in[1];
    const float* cb3 = (const float*)d_in[2];
    const float* rw  = (const float*)d_in[3];
    const float* rb  = (const float*)d_in[4];
    const float* clw = (const float*)d_in[5];
    const float* clb = (const float*)d_in[6];
    float* out = (float*)d_out;

    char* p = (char*)d_ws;
    auto alloc = [&](size_t n) { char* r = p; p += (n + 255) & ~(size_t)255; return r; };
    float*  part   = (float*)alloc((size_t)CS * 512 * NPIX * 4);  // 20.5 MB
    float*  feat   = (float*)alloc((size_t)512 * NPIX * 4);       // 5.12 MB
    float*  regcls = (float*)alloc((size_t)54 * NPIX * 4);        // 0.54 MB
    float4* boxes  = (float4*)alloc((size_t)NANCH * 16);          // 0.36 MB
    unsigned long long* keys = (unsigned long long*)alloc((size_t)NKEY * 8);
    int*    rank   = (int*)alloc((size_t)NANCH * 4);
    float4* sboxes = (float4*)alloc((size_t)PRE * 16);
    unsigned long long* mask = (unsigned long long*)alloc((size_t)PRE * MW * 8); // 4.6 MB

    hipMemsetAsync(rank, 0, (size_t)NANCH * 4, stream);
    conv3x3_part  <<<dim3(32, 40, CS), 64, 0, stream>>>(x, cw3, part);
    reduce_leaky  <<<5000, 256, 0, stream>>>(part, cb3, feat);
    conv1x1_heads <<<dim3(40, 3), 64, 0, stream>>>(feat, rw, rb, clw, clb, regcls);
    decodeK       <<<88, 256, 0, stream>>>(regcls, boxes, keys);
    rankK         <<<dim3(88, 8), 256, 0, stream>>>(keys, rank);
    scatterK      <<<88, 256, 0, stream>>>(boxes, rank, sboxes);
    nmsMaskK      <<<dim3(375, 4), 256, 0, stream>>>(sboxes, mask);
    nmsScanOutK   <<<1, 256, 0, stream>>>(mask, sboxes, out);
}

// Round 4
// 814.768 us; speedup vs baseline: 2.5347x; 1.9398x over previous
//
#include <hip/hip_runtime.h>

// ---------------------------------------------------------------------------
// RPN forward, MI355X. Only batch element 7 contributes to the output.
// conv3x3 (cin-split partials, no LDS) -> reduce+leaky -> 1x1 heads ->
// decode/score/key -> O(N^2) rank sort -> top-6000 -> NMS bitmask
// (reference's yy2=max bug replicated) -> word-serial single-wave scan ->
// 300x4 boxes. Deterministic fp32 everywhere (no float atomics).
// ---------------------------------------------------------------------------

#define NPIX 2500      // 50*50
#define NANCH 22500    // 2500*9
#define NKEY 22528     // NANCH padded to 88*256 (sentinel tail)
#define PRE 6000
#define MASKW 94       // ceil(6000/64) usable words
#define MW 96          // storage stride in words
#define JCHUNK 1536    // j-chunk for mask kernel (24 words)
#define CS 4           // cin splits for conv3x3
#define CGRP 128       // cin per split

// ---------------- conv 3x3 partials: no LDS, lane=pixel, wave=16 oc --------
// grid (32 ocGroups, 40 pixel tiles, 4 cin groups), block 64 (1 wave).
__global__ __launch_bounds__(64, 5) void conv3x3_part(
    const float* __restrict__ x,    // batch-7 base (512,50,50)
    const float* __restrict__ wt,   // (512,512,3,3)
    float* __restrict__ part)       // (CS,512,2500)
{
    const int lane = threadIdx.x;
    const int tile = blockIdx.y;
    const int ocb  = blockIdx.x * 16;
    const int cing = blockIdx.z * CGRP;

    int p = tile * 64 + lane;
    const bool active = (p < NPIX);
    if (!active) p = NPIX - 1;
    const int hh = p / 50;
    const int ww = p - hh * 50;

    int   soff[9];
    float mk[9];
    #pragma unroll
    for (int r = 0; r < 3; ++r) {
        #pragma unroll
        for (int c = 0; c < 3; ++c) {
            const int gr = hh + r - 1, gc = ww + c - 1;
            const bool ok = (gr >= 0) & (gr < 50) & (gc >= 0) & (gc < 50);
            soff[r * 3 + c] = ok ? (gr * 50 + gc) : 0;
            mk[r * 3 + c]   = ok ? 1.0f : 0.0f;
        }
    }

    float acc[16];
    #pragma unroll
    for (int o = 0; o < 16; ++o) acc[o] = 0.f;

    for (int cin = 0; cin < CGRP; ++cin) {
        const float* xp = x + (size_t)(cing + cin) * NPIX;
        float v[9];
        #pragma unroll
        for (int k = 0; k < 9; ++k)
            v[k] = xp[soff[k]] * mk[k];
        const float* wbase = wt + ((size_t)ocb * 512 + (cing + cin)) * 9;
        #pragma unroll
        for (int o = 0; o < 16; ++o) {
            const float* w = wbase + (size_t)o * 4608;  // wave-uniform -> s_load
            #pragma unroll
            for (int t = 0; t < 9; ++t)
                acc[o] = fmaf(w[t], v[t], acc[o]);
        }
    }

    if (active) {
        float* dst = part + ((size_t)blockIdx.z * 512 + ocb) * NPIX + p;
        #pragma unroll
        for (int o = 0; o < 16; ++o)
            dst[(size_t)o * NPIX] = acc[o];
    }
}

// ---------------- reduce partials + bias + leaky ---------------------------
__global__ __launch_bounds__(256) void reduce_leaky(
    const float* __restrict__ part, const float* __restrict__ bias,
    float* __restrict__ feat)
{
    const int i = blockIdx.x * 256 + threadIdx.x;
    if (i >= 512 * NPIX) return;
    const int oc = i / NPIX;
    float s = part[i];
    s += part[(size_t)1 * 512 * NPIX + i];
    s += part[(size_t)2 * 512 * NPIX + i];
    s += part[(size_t)3 * 512 * NPIX + i];
    s += bias[oc];
    s = (s >= 0.f) ? s : 0.01f * s;
    feat[i] = s;
}

// ---------------- 1x1 heads: reg (36) + cls (18), stored oc-major ----------
__global__ __launch_bounds__(64) void conv1x1_heads(
    const float* __restrict__ feat,
    const float* __restrict__ rw, const float* __restrict__ rb,
    const float* __restrict__ cw, const float* __restrict__ cb,
    float* __restrict__ regcls)   // (54, 2500)
{
    const int tid  = threadIdx.x;
    const int pix0 = blockIdx.x * 64 + tid;
    const bool act = (pix0 < NPIX);
    const int pix  = act ? pix0 : (NPIX - 1);
    const int chunk = blockIdx.y;
    const float* wb; const float* bb; int ocbase;
    if (chunk == 0)      { wb = rw;            bb = rb;      ocbase = 0;  }
    else if (chunk == 1) { wb = rw + 18 * 512; bb = rb + 18; ocbase = 18; }
    else                 { wb = cw;            bb = cb;      ocbase = 36; }

    float acc[18];
    #pragma unroll
    for (int k = 0; k < 18; ++k) acc[k] = 0.f;

    for (int cin = 0; cin < 512; ++cin) {
        const float v = feat[(size_t)cin * NPIX + pix];
        #pragma unroll
        for (int k = 0; k < 18; ++k)
            acc[k] = fmaf(wb[k * 512 + cin], v, acc[k]);
    }
    if (act) {
        #pragma unroll
        for (int k = 0; k < 18; ++k)
            regcls[(size_t)(ocbase + k) * NPIX + pix] = acc[k] + bb[k];
    }
}

// ---------------- decode: anchors, softmax score, sortable key -------------
__global__ __launch_bounds__(256) void decodeK(
    const float* __restrict__ regcls,
    float4* __restrict__ boxes,
    unsigned long long* __restrict__ keys)
{
    const int i = blockIdx.x * 256 + threadIdx.x;
    if (i >= NANCH) {
        if (i < NKEY) keys[i] = 0xFFFFFFFFFFFFFFFFull;  // sentinel: > all keys
        return;
    }
    const int pos = i / 9;
    const int a   = i - pos * 9;
    const int hh  = pos / 50;
    const int wwp = pos - hh * 50;
    const int r = a / 3, s = a - r * 3;

    const float base_s[3] = {128.f, 256.f, 512.f};
    const float sq [3] = {0.70710678118654752440f, 1.0f, 1.41421356237309504880f};
    const float sqi[3] = {1.41421356237309504880f, 1.0f, 0.70710678118654752440f};
    const float hs = base_s[s] * sq[r];
    const float ws = base_s[s] * sqi[r];
    const float cx = (float)(hh * 16 + 8);    // cx indexed by h (reference quirk)
    const float cy = (float)(wwp * 16 + 8);
    const float ax = cx - ws * 0.5f;
    const float ay = cy - hs * 0.5f;

    const float pr0 = regcls[(size_t)(a * 4 + 0) * NPIX + pos];
    const float pr1 = regcls[(size_t)(a * 4 + 1) * NPIX + pos];
    const float pr2 = regcls[(size_t)(a * 4 + 2) * NPIX + pos];
    const float pr3 = regcls[(size_t)(a * 4 + 3) * NPIX + pos];
    const float c0  = regcls[(size_t)(36 + a * 2 + 0) * NPIX + pos];
    const float c1  = regcls[(size_t)(36 + a * 2 + 1) * NPIX + pos];

    const float m  = fmaxf(c0, c1);
    const float e0 = expf(c0 - m);
    const float e1 = expf(c1 - m);
    const float score = e1 / (e0 + e1);

    const float t0 = pr0 + ax;
    const float t1 = pr1 + ay;
    const float hi = 799.0f;
    const float rx1 = fminf(fmaxf(t0, 0.f), hi);
    const float ry1 = fminf(fmaxf(t1, 0.f), hi);
    const float rx2 = fminf(fmaxf((t0 + pr2) + ws, 0.f), hi);
    const float ry2 = fminf(fmaxf((t1 + pr3) + hs, 0.f), hi);
    const float bw = pr2 + ws;
    const float bh = pr3 + hs;
    const bool valid = (bw >= 16.f) && (bh >= 16.f);
    const float sc = valid ? score : -__builtin_inff();

    unsigned u = __float_as_uint(sc);
    u = (u & 0x80000000u) ? ~u : (u | 0x80000000u);  // monotone ascending map
    const unsigned k32 = ~u;                          // descending score
    keys[i]  = ((unsigned long long)k32 << 32) | (unsigned)i;  // tie: asc index
    boxes[i] = make_float4(rx1, ry1, rx2, ry2);
}

// ---------------- O(N^2) rank (stable argsort position) --------------------
__global__ __launch_bounds__(256) void rankK(
    const unsigned long long* __restrict__ keys, int* __restrict__ rank)
{
    const int i = blockIdx.x * 256 + threadIdx.x;
    const unsigned long long my = (i < NANCH) ? keys[i] : 0ull;
    const unsigned long long* kj = keys + blockIdx.y * 2816;
    int cnt = 0;
    for (int t = 0; t < 2816; t += 8) {
        #pragma unroll
        for (int q = 0; q < 8; ++q)
            cnt += (kj[t + q] < my) ? 1 : 0;
    }
    if (i < NANCH) atomicAdd(&rank[i], cnt);
}

__global__ __launch_bounds__(256) void scatterK(
    const float4* __restrict__ boxes, const int* __restrict__ rank,
    float4* __restrict__ sboxes)
{
    const int i = blockIdx.x * 256 + threadIdx.x;
    if (i < NANCH) {
        const int r = rank[i];
        if (r < PRE) sboxes[r] = boxes[i];
    }
}

// ---------------- NMS suppression bitmask (reference bug replicated) -------
__global__ __launch_bounds__(256) void nmsMaskK(
    const float4* __restrict__ sb, unsigned long long* __restrict__ mask)
{
    __shared__ float sx1[JCHUNK], sy1[JCHUNK], sx2[JCHUNK], sy2[JCHUNK], sar[JCHUNK];
    const int tid = threadIdx.x;
    const int jbase = blockIdx.y * JCHUNK;
    for (int t = tid; t < JCHUNK; t += 256) {
        const int j = jbase + t;
        if (j < PRE) {
            const float4 b = sb[j];
            sx1[t] = b.x; sy1[t] = b.y; sx2[t] = b.z; sy2[t] = b.w;
            sar[t] = (b.z - b.x + 1.f) * (b.w - b.y + 1.f);
        } else {
            sx1[t] = 0.f; sy1[t] = 0.f; sx2[t] = -1.f; sy2[t] = 0.f; sar[t] = 0.f;
        }
    }
    __syncthreads();
    const int i = blockIdx.x * 16 + (tid >> 4);
    const float4 bi = sb[i];
    const float x1 = bi.x, y1 = bi.y, x2 = bi.z, y2 = bi.w;
    const float ar = (x2 - x1 + 1.f) * (y2 - y1 + 1.f);
    for (int w = (tid & 15); w < 24; w += 16) {
        unsigned long long bits = 0ull;
        const int l0 = w * 64;
        for (int u = 0; u < 64; ++u) {
            const int j = jbase + l0 + u;
            if (j > i && j < PRE) {
                const int l = l0 + u;
                const float xx1 = fmaxf(x1, sx1[l]);
                const float yy1 = fmaxf(y1, sy1[l]);
                const float xx2 = fminf(x2, sx2[l]);
                const float yy2 = fmaxf(y2, sy2[l]);        // reference bug: max
                const float wv = fmaxf(0.f, xx2 - xx1 + 1.f);
                const float hv = fmaxf(0.f, yy2 - yy1 + 1.f);
                const float inter = wv * hv;
                const float ov = inter / ((ar + sar[l]) - inter);  // precise div
                if (ov > 0.7f) bits |= (1ull << u);
            }
        }
        mask[(size_t)i * MW + blockIdx.y * 24 + w] = bits;
    }
}

// ---------------- word-serial NMS scan + output (single wave) --------------
// Lane l holds remv words l and 64+l in registers. Per 64-candidate block g:
// diag word mask[g*64+b][g] prefetched one block ahead (lane b); the serial
// loop is pure ALU (ctz + 2 readlanes per candidate); only KEPT rows are
// fetched from global (2-wide pairing) and OR-ed into remv. No barriers.
__global__ __launch_bounds__(64) void nmsScanOutK(
    const unsigned long long* __restrict__ mask,
    const float4* __restrict__ sb,
    float* __restrict__ out)
{
    __shared__ int sKept[300];
    __shared__ unsigned long long sKeepW[MASKW];
    const int lane = threadIdx.x;

    unsigned long long rem0 = 0ull, rem1 = 0ull;   // lane l: words l, 64+l
    int cnt = 0;
    int done = 0;

    unsigned long long diag = mask[(size_t)lane * MW + 0];   // block 0 diag

    for (int g = 0; g < MASKW && !done; ++g) {
        // prefetch next block's diagonal word
        unsigned long long diag_next = 0ull;
        if (g + 1 < MASKW) {
            const int r2 = (g + 1) * 64 + lane;
            if (r2 < PRE) diag_next = mask[(size_t)r2 * MW + (g + 1)];
        }
        // current remv word g (broadcast from owning lane)
        unsigned long long cur;
        {
            unsigned lo, hi;
            if (g < 64) {
                lo = __builtin_amdgcn_readlane((unsigned)rem0, g);
                hi = __builtin_amdgcn_readlane((unsigned)(rem0 >> 32), g);
            } else {
                lo = __builtin_amdgcn_readlane((unsigned)rem1, g - 64);
                hi = __builtin_amdgcn_readlane((unsigned)(rem1 >> 32), g - 64);
            }
            cur = ((unsigned long long)hi << 32) | lo;
        }
        const unsigned long long valid =
            (g == MASKW - 1) ? 0x0000FFFFFFFFFFFFull : ~0ull;   // 48 tail bits
        unsigned long long procd = 0ull;
        unsigned long long kb = 0ull;

        for (;;) {                                   // serial, pure ALU
            const unsigned long long nd = (~cur) & valid & ~procd;
            if (!nd) break;
            const int b = __builtin_ctzll(nd);
            procd |= (1ull << b);
            if (lane == 0 && cnt < 300) sKept[cnt] = g * 64 + b;
            ++cnt;
            kb |= (1ull << b);
            if (cnt >= 300) { done = 1; break; }
            const unsigned dlo = __builtin_amdgcn_readlane((unsigned)diag, b);
            const unsigned dhi = __builtin_amdgcn_readlane((unsigned)(diag >> 32), b);
            cur |= ((unsigned long long)dhi << 32) | dlo;
        }
        if (lane == 0) sKeepW[g] = kb;

        if (!done) {                                 // OR kept rows into remv
            unsigned long long k2 = kb;
            while (k2) {
                const int b0 = __builtin_ctzll(k2); k2 &= k2 - 1;
                const unsigned long long* p0 = mask + (size_t)(g * 64 + b0) * MW;
                unsigned long long a0 = p0[lane];
                unsigned long long a1 = (lane < MASKW - 64) ? p0[64 + lane] : 0ull;
                if (k2) {                            // pair a second kept row
                    const int b1 = __builtin_ctzll(k2); k2 &= k2 - 1;
                    const unsigned long long* p1 = mask + (size_t)(g * 64 + b1) * MW;
                    a0 |= p1[lane];
                    a1 |= (lane < MASKW - 64) ? p1[64 + lane] : 0ull;
                }
                rem0 |= a0;
                rem1 |= a1;
            }
        }
        diag = diag_next;
    }

    __syncthreads();                                 // publish sKeepW / sKept

    if (cnt < 300) {                                 // filler: unkept, asc index
        int c = cnt;
        for (int g = 0; g < MASKW && c < 300; ++g) {
            const unsigned long long valid =
                (g == MASKW - 1) ? 0x0000FFFFFFFFFFFFull : ~0ull;
            unsigned long long u = (~sKeepW[g]) & valid;
            while (u && c < 300) {
                const int b = __builtin_ctzll(u); u &= u - 1;
                if (lane == 0) sKept[c] = g * 64 + b;
                ++c;
            }
        }
    }
    __syncthreads();

    for (int s = lane; s < 300; s += 64) {
        const float4 b = sb[sKept[s]];
        out[s * 4 + 0] = b.x;
        out[s * 4 + 1] = b.y;
        out[s * 4 + 2] = b.z - b.x + 1.0f;
        out[s * 4 + 3] = b.w - b.y + 1.0f;
    }
}

// ---------------------------------------------------------------------------
extern "C" void kernel_launch(void* const* d_in, const int* in_sizes, int n_in,
                              void* d_out, int out_size, void* d_ws, size_t ws_size,
                              hipStream_t stream)
{
    (void)in_sizes; (void)n_in; (void)out_size; (void)ws_size;
    const float* x   = (const float*)d_in[0] + (size_t)7 * 512 * NPIX; // batch 7
    const float* cw3 = (const float*)d_in[1];
    const float* cb3 = (const float*)d_in[2];
    const float* rw  = (const float*)d_in[3];
    const float* rb  = (const float*)d_in[4];
    const float* clw = (const float*)d_in[5];
    const float* clb = (const float*)d_in[6];
    float* out = (float*)d_out;

    char* p = (char*)d_ws;
    auto alloc = [&](size_t n) { char* r = p; p += (n + 255) & ~(size_t)255; return r; };
    float*  part   = (float*)alloc((size_t)CS * 512 * NPIX * 4);  // 20.5 MB
    float*  feat   = (float*)alloc((size_t)512 * NPIX * 4);       // 5.12 MB
    float*  regcls = (float*)alloc((size_t)54 * NPIX * 4);        // 0.54 MB
    float4* boxes  = (float4*)alloc((size_t)NANCH * 16);          // 0.36 MB
    unsigned long long* keys = (unsigned long long*)alloc((size_t)NKEY * 8);
    int*    rank   = (int*)alloc((size_t)NANCH * 4);
    float4* sboxes = (float4*)alloc((size_t)PRE * 16);
    unsigned long long* mask = (unsigned long long*)alloc((size_t)PRE * MW * 8); // 4.6 MB

    hipMemsetAsync(rank, 0, (size_t)NANCH * 4, stream);
    conv3x3_part  <<<dim3(32, 40, CS), 64, 0, stream>>>(x, cw3, part);
    reduce_leaky  <<<5000, 256, 0, stream>>>(part, cb3, feat);
    conv1x1_heads <<<dim3(40, 3), 64, 0, stream>>>(feat, rw, rb, clw, clb, regcls);
    decodeK       <<<88, 256, 0, stream>>>(regcls, boxes, keys);
    rankK         <<<dim3(88, 8), 256, 0, stream>>>(keys, rank);
    scatterK      <<<88, 256, 0, stream>>>(boxes, rank, sboxes);
    nmsMaskK      <<<dim3(375, 4), 256, 0, stream>>>(sboxes, mask);
    nmsScanOutK   <<<1, 64, 0, stream>>>(mask, sboxes, out);
}

// Round 5
// 734.100 us; speedup vs baseline: 2.8132x; 1.1099x over previous
//
#include <hip/hip_runtime.h>

// ---------------------------------------------------------------------------
// RPN forward, MI355X. Only batch element 7 contributes to the output.
// conv3x3 (cin-split partials, 2px x 16oc register tile) -> reduce+leaky ->
// 1x1 heads (4-wave cin split) -> decode/score/key -> O(N^2) rank sort ->
// top-6000 -> NMS bitmask (reference's yy2=max bug replicated) ->
// word-serial single-wave scan with speculative row prefetch -> 300x4 boxes.
// Deterministic fp32 everywhere (no float atomics).
// ---------------------------------------------------------------------------

#define NPIX 2500      // 50*50
#define NANCH 22500    // 2500*9
#define NKEY 22528     // NANCH padded to 88*256 (sentinel tail)
#define PRE 6000
#define MASKW 94       // ceil(6000/64) usable words
#define MW 96          // storage stride in words
#define JCHUNK 1536    // j-chunk for mask kernel (24 words)
#define CS 4           // cin splits for conv3x3
#define CGRP 128       // cin per split
#define SPEC 12        // speculative row-prefetch slots in scan

// ---------------- conv 3x3 partials: 2 pixels x 16 oc per lane -------------
// grid (32 ocGroups, 20 pixel tiles, 4 cin groups), block 64 (1 wave).
// Lane handles pixels p and p+1280; weights wave-uniform s_load (288 FMA per
// 144 weight words -> halved weight stream vs 1-px tiling).
__global__ __launch_bounds__(64) void conv3x3_part(
    const float* __restrict__ x,    // batch-7 base (512,50,50)
    const float* __restrict__ wt,   // (512,512,3,3)
    float* __restrict__ part)       // (CS,512,2500)
{
    const int lane = threadIdx.x;
    const int tile = blockIdx.y;                 // 0..19
    const int ocb  = blockIdx.x * 16;
    const int cing = blockIdx.z * CGRP;

    const int p0 = tile * 64 + lane;             // < 1280 always
    const int p1 = p0 + 1280;
    const bool act1 = (p1 < NPIX);
    const int p1c = act1 ? p1 : (NPIX - 1);

    int   soff[18];
    float mk[18];
    {
        const int hh0 = p0 / 50,  ww0 = p0 - hh0 * 50;
        const int hh1 = p1c / 50, ww1 = p1c - hh1 * 50;
        #pragma unroll
        for (int r = 0; r < 3; ++r) {
            #pragma unroll
            for (int c = 0; c < 3; ++c) {
                int gr = hh0 + r - 1, gc = ww0 + c - 1;
                bool ok = (gr >= 0) & (gr < 50) & (gc >= 0) & (gc < 50);
                soff[r * 3 + c] = ok ? (gr * 50 + gc) : 0;
                mk[r * 3 + c]   = ok ? 1.0f : 0.0f;
                gr = hh1 + r - 1; gc = ww1 + c - 1;
                ok = (gr >= 0) & (gr < 50) & (gc >= 0) & (gc < 50);
                soff[9 + r * 3 + c] = ok ? (gr * 50 + gc) : 0;
                mk[9 + r * 3 + c]   = ok ? 1.0f : 0.0f;
            }
        }
    }

    float acc0[16], acc1[16];
    #pragma unroll
    for (int o = 0; o < 16; ++o) { acc0[o] = 0.f; acc1[o] = 0.f; }

    for (int cin = 0; cin < CGRP; ++cin) {
        const float* xp = x + (size_t)(cing + cin) * NPIX;
        float v[18];
        #pragma unroll
        for (int k = 0; k < 18; ++k)
            v[k] = xp[soff[k]] * mk[k];
        const float* wbase = wt + ((size_t)ocb * 512 + (cing + cin)) * 9;
        #pragma unroll
        for (int o = 0; o < 16; ++o) {
            const float* w = wbase + (size_t)o * 4608;  // wave-uniform -> s_load
            #pragma unroll
            for (int t = 0; t < 9; ++t) {
                acc0[o] = fmaf(w[t], v[t],     acc0[o]);
                acc1[o] = fmaf(w[t], v[9 + t], acc1[o]);
            }
        }
    }

    float* dst = part + ((size_t)blockIdx.z * 512 + ocb) * NPIX;
    #pragma unroll
    for (int o = 0; o < 16; ++o) {
        dst[(size_t)o * NPIX + p0] = acc0[o];
        if (act1) dst[(size_t)o * NPIX + p1] = acc1[o];
    }
}

// ---------------- reduce partials + bias + leaky ---------------------------
__global__ __launch_bounds__(256) void reduce_leaky(
    const float* __restrict__ part, const float* __restrict__ bias,
    float* __restrict__ feat)
{
    const int i = blockIdx.x * 256 + threadIdx.x;
    if (i >= 512 * NPIX) return;
    const int oc = i / NPIX;
    float s = part[i];
    s += part[(size_t)1 * 512 * NPIX + i];
    s += part[(size_t)2 * 512 * NPIX + i];
    s += part[(size_t)3 * 512 * NPIX + i];
    s += bias[oc];
    s = (s >= 0.f) ? s : 0.01f * s;
    feat[i] = s;
}

// ---------------- 1x1 heads: 4-wave cin split + LDS tree reduce ------------
// grid (40 pixel tiles of 64, 3 oc-chunks of 18), block 256 (4 waves).
// Wave w sums cin [w*128, w*128+128); deterministic ((w0+w1)+w2)+w3.
__global__ __launch_bounds__(256) void conv1x1_heads(
    const float* __restrict__ feat,
    const float* __restrict__ rw, const float* __restrict__ rb,
    const float* __restrict__ cw, const float* __restrict__ cb,
    float* __restrict__ regcls)   // (54, 2500)
{
    __shared__ float sAcc[3][18][64];
    const int tid  = threadIdx.x;
    const int lane = tid & 63;
    const int wv   = tid >> 6;
    const int pix0 = blockIdx.x * 64 + lane;
    const bool act = (pix0 < NPIX);
    const int pix  = act ? pix0 : (NPIX - 1);
    const int chunk = blockIdx.y;
    const float* wb; const float* bb; int ocbase;
    if (chunk == 0)      { wb = rw;            bb = rb;      ocbase = 0;  }
    else if (chunk == 1) { wb = rw + 18 * 512; bb = rb + 18; ocbase = 18; }
    else                 { wb = cw;            bb = cb;      ocbase = 36; }

    float acc[18];
    #pragma unroll
    for (int k = 0; k < 18; ++k) acc[k] = 0.f;

    const int c0 = wv * 128;
    for (int cin = c0; cin < c0 + 128; ++cin) {
        const float v = feat[(size_t)cin * NPIX + pix];
        #pragma unroll
        for (int k = 0; k < 18; ++k)
            acc[k] = fmaf(wb[k * 512 + cin], v, acc[k]);
    }
    if (wv > 0) {
        #pragma unroll
        for (int k = 0; k < 18; ++k) sAcc[wv - 1][k][lane] = acc[k];
    }
    __syncthreads();
    if (wv == 0 && act) {
        #pragma unroll
        for (int k = 0; k < 18; ++k) {
            float s = acc[k];
            s += sAcc[0][k][lane];
            s += sAcc[1][k][lane];
            s += sAcc[2][k][lane];
            regcls[(size_t)(ocbase + k) * NPIX + pix] = s + bb[k];
        }
    }
}

// ---------------- decode: anchors, softmax score, sortable key -------------
__global__ __launch_bounds__(256) void decodeK(
    const float* __restrict__ regcls,
    float4* __restrict__ boxes,
    unsigned long long* __restrict__ keys)
{
    const int i = blockIdx.x * 256 + threadIdx.x;
    if (i >= NANCH) {
        if (i < NKEY) keys[i] = 0xFFFFFFFFFFFFFFFFull;  // sentinel: > all keys
        return;
    }
    const int pos = i / 9;
    const int a   = i - pos * 9;
    const int hh  = pos / 50;
    const int wwp = pos - hh * 50;
    const int r = a / 3, s = a - r * 3;

    const float base_s[3] = {128.f, 256.f, 512.f};
    const float sq [3] = {0.70710678118654752440f, 1.0f, 1.41421356237309504880f};
    const float sqi[3] = {1.41421356237309504880f, 1.0f, 0.70710678118654752440f};
    const float hs = base_s[s] * sq[r];
    const float ws = base_s[s] * sqi[r];
    const float cx = (float)(hh * 16 + 8);    // cx indexed by h (reference quirk)
    const float cy = (float)(wwp * 16 + 8);
    const float ax = cx - ws * 0.5f;
    const float ay = cy - hs * 0.5f;

    const float pr0 = regcls[(size_t)(a * 4 + 0) * NPIX + pos];
    const float pr1 = regcls[(size_t)(a * 4 + 1) * NPIX + pos];
    const float pr2 = regcls[(size_t)(a * 4 + 2) * NPIX + pos];
    const float pr3 = regcls[(size_t)(a * 4 + 3) * NPIX + pos];
    const float c0  = regcls[(size_t)(36 + a * 2 + 0) * NPIX + pos];
    const float c1  = regcls[(size_t)(36 + a * 2 + 1) * NPIX + pos];

    const float m  = fmaxf(c0, c1);
    const float e0 = expf(c0 - m);
    const float e1 = expf(c1 - m);
    const float score = e1 / (e0 + e1);

    const float t0 = pr0 + ax;
    const float t1 = pr1 + ay;
    const float hi = 799.0f;
    const float rx1 = fminf(fmaxf(t0, 0.f), hi);
    const float ry1 = fminf(fmaxf(t1, 0.f), hi);
    const float rx2 = fminf(fmaxf((t0 + pr2) + ws, 0.f), hi);
    const float ry2 = fminf(fmaxf((t1 + pr3) + hs, 0.f), hi);
    const float bw = pr2 + ws;
    const float bh = pr3 + hs;
    const bool valid = (bw >= 16.f) && (bh >= 16.f);
    const float sc = valid ? score : -__builtin_inff();

    unsigned u = __float_as_uint(sc);
    u = (u & 0x80000000u) ? ~u : (u | 0x80000000u);  // monotone ascending map
    const unsigned k32 = ~u;                          // descending score
    keys[i]  = ((unsigned long long)k32 << 32) | (unsigned)i;  // tie: asc index
    boxes[i] = make_float4(rx1, ry1, rx2, ry2);
}

// ---------------- O(N^2) rank (stable argsort position) --------------------
__global__ __launch_bounds__(256) void rankK(
    const unsigned long long* __restrict__ keys, int* __restrict__ rank)
{
    const int i = blockIdx.x * 256 + threadIdx.x;
    const unsigned long long my = (i < NANCH) ? keys[i] : 0ull;
    const unsigned long long* kj = keys + blockIdx.y * 2816;
    int cnt = 0;
    for (int t = 0; t < 2816; t += 8) {
        #pragma unroll
        for (int q = 0; q < 8; ++q)
            cnt += (kj[t + q] < my) ? 1 : 0;
    }
    if (i < NANCH) atomicAdd(&rank[i], cnt);
}

__global__ __launch_bounds__(256) void scatterK(
    const float4* __restrict__ boxes, const int* __restrict__ rank,
    float4* __restrict__ sboxes)
{
    const int i = blockIdx.x * 256 + threadIdx.x;
    if (i < NANCH) {
        const int r = rank[i];
        if (r < PRE) sboxes[r] = boxes[i];
    }
}

// ---------------- NMS suppression bitmask (reference bug replicated) -------
__global__ __launch_bounds__(256) void nmsMaskK(
    const float4* __restrict__ sb, unsigned long long* __restrict__ mask)
{
    __shared__ float sx1[JCHUNK], sy1[JCHUNK], sx2[JCHUNK], sy2[JCHUNK], sar[JCHUNK];
    const int tid = threadIdx.x;
    const int jbase = blockIdx.y * JCHUNK;
    for (int t = tid; t < JCHUNK; t += 256) {
        const int j = jbase + t;
        if (j < PRE) {
            const float4 b = sb[j];
            sx1[t] = b.x; sy1[t] = b.y; sx2[t] = b.z; sy2[t] = b.w;
            sar[t] = (b.z - b.x + 1.f) * (b.w - b.y + 1.f);
        } else {
            sx1[t] = 0.f; sy1[t] = 0.f; sx2[t] = -1.f; sy2[t] = 0.f; sar[t] = 0.f;
        }
    }
    __syncthreads();
    const int i = blockIdx.x * 16 + (tid >> 4);
    const float4 bi = sb[i];
    const float x1 = bi.x, y1 = bi.y, x2 = bi.z, y2 = bi.w;
    const float ar = (x2 - x1 + 1.f) * (y2 - y1 + 1.f);
    for (int w = (tid & 15); w < 24; w += 16) {
        unsigned long long bits = 0ull;
        const int l0 = w * 64;
        for (int u = 0; u < 64; ++u) {
            const int j = jbase + l0 + u;
            if (j > i && j < PRE) {
                const int l = l0 + u;
                const float xx1 = fmaxf(x1, sx1[l]);
                const float yy1 = fmaxf(y1, sy1[l]);
                const float xx2 = fminf(x2, sx2[l]);
                const float yy2 = fmaxf(y2, sy2[l]);        // reference bug: max
                const float wv = fmaxf(0.f, xx2 - xx1 + 1.f);
                const float hv = fmaxf(0.f, yy2 - yy1 + 1.f);
                const float inter = wv * hv;
                const float ov = inter / ((ar + sar[l]) - inter);  // precise div
                if (ov > 0.7f) bits |= (1ull << u);
            }
        }
        mask[(size_t)i * MW + blockIdx.y * 24 + w] = bits;
    }
}

// ---------------- word-serial NMS scan + output (single wave) --------------
// Lane l holds remv words l and 64+l in registers. Per 64-candidate block g:
// diag word prefetched one block ahead; up to SPEC candidate rows prefetched
// in parallel BEFORE the serial ffs loop (kept rows OR from the prefetched
// regs; overflow falls back to a direct load). Candidate bits are processed
// in strictly increasing order, so a single slot pointer matches prefetches.
__global__ __launch_bounds__(64) void nmsScanOutK(
    const unsigned long long* __restrict__ mask,
    const float4* __restrict__ sb,
    float* __restrict__ out)
{
    __shared__ int sKept[300];
    __shared__ unsigned long long sKeepW[MASKW];
    const int lane = threadIdx.x;

    unsigned long long rem0 = 0ull, rem1 = 0ull;   // lane l: words l, 64+l
    int cnt = 0;
    int done = 0;

    unsigned long long diag = mask[(size_t)lane * MW + 0];   // block 0 diag

    for (int g = 0; g < MASKW && !done; ++g) {
        unsigned long long diag_next = 0ull;
        if (g + 1 < MASKW) {
            const int r2 = (g + 1) * 64 + lane;
            if (r2 < PRE) diag_next = mask[(size_t)r2 * MW + (g + 1)];
        }
        unsigned long long cur;
        {
            unsigned lo, hi;
            if (g < 64) {
                lo = __builtin_amdgcn_readlane((unsigned)rem0, g);
                hi = __builtin_amdgcn_readlane((unsigned)(rem0 >> 32), g);
            } else {
                lo = __builtin_amdgcn_readlane((unsigned)rem1, g - 64);
                hi = __builtin_amdgcn_readlane((unsigned)(rem1 >> 32), g - 64);
            }
            cur = ((unsigned long long)hi << 32) | lo;
        }
        const unsigned long long valid =
            (g == MASKW - 1) ? 0x0000FFFFFFFFFFFFull : ~0ull;   // 48 tail bits

        // speculative parallel prefetch of candidate rows
        unsigned long long sp0[SPEC], sp1[SPEC];
        int sbit[SPEC];
        int ns = 0;
        {
            unsigned long long t = (~cur) & valid;
            while (t && ns < SPEC) {
                const int b = __builtin_ctzll(t); t &= t - 1;
                const unsigned long long* pr = mask + (size_t)(g * 64 + b) * MW;
                sp0[ns] = pr[lane];
                sp1[ns] = (lane < MASKW - 64) ? pr[64 + lane] : 0ull;
                sbit[ns] = b;
                ++ns;
            }
        }

        unsigned long long procd = 0ull;
        unsigned long long kb = 0ull;
        int slot = 0;

        for (;;) {                                   // serial, pure ALU + reg ORs
            const unsigned long long nd = (~cur) & valid & ~procd;
            if (!nd) break;
            const int b = __builtin_ctzll(nd);
            procd |= (1ull << b);
            if (lane == 0 && cnt < 300) sKept[cnt] = g * 64 + b;
            ++cnt;
            kb |= (1ull << b);
            if (cnt >= 300) { done = 1; break; }
            const unsigned dlo = __builtin_amdgcn_readlane((unsigned)diag, b);
            const unsigned dhi = __builtin_amdgcn_readlane((unsigned)(diag >> 32), b);
            cur |= ((unsigned long long)dhi << 32) | dlo;
            // OR this kept row into remv (prefetched slot if available)
            while (slot < ns && sbit[slot] < b) ++slot;
            if (slot < ns && sbit[slot] == b) {
                rem0 |= sp0[slot];
                rem1 |= sp1[slot];
                ++slot;
            } else {
                const unsigned long long* pr = mask + (size_t)(g * 64 + b) * MW;
                rem0 |= pr[lane];
                rem1 |= (lane < MASKW - 64) ? pr[64 + lane] : 0ull;
            }
        }
        if (lane == 0) sKeepW[g] = kb;
        diag = diag_next;
    }

    __syncthreads();                                 // publish sKeepW / sKept

    if (cnt < 300) {                                 // filler: unkept, asc index
        int c = cnt;
        for (int g = 0; g < MASKW && c < 300; ++g) {
            const unsigned long long valid =
                (g == MASKW - 1) ? 0x0000FFFFFFFFFFFFull : ~0ull;
            unsigned long long u = (~sKeepW[g]) & valid;
            while (u && c < 300) {
                const int b = __builtin_ctzll(u); u &= u - 1;
                if (lane == 0) sKept[c] = g * 64 + b;
                ++c;
            }
        }
    }
    __syncthreads();

    for (int s = lane; s < 300; s += 64) {
        const float4 b = sb[sKept[s]];
        out[s * 4 + 0] = b.x;
        out[s * 4 + 1] = b.y;
        out[s * 4 + 2] = b.z - b.x + 1.0f;
        out[s * 4 + 3] = b.w - b.y + 1.0f;
    }
}

// ---------------------------------------------------------------------------
extern "C" void kernel_launch(void* const* d_in, const int* in_sizes, int n_in,
                              void* d_out, int out_size, void* d_ws, size_t ws_size,
                              hipStream_t stream)
{
    (void)in_sizes; (void)n_in; (void)out_size; (void)ws_size;
    const float* x   = (const float*)d_in[0] + (size_t)7 * 512 * NPIX; // batch 7
    const float* cw3 = (const float*)d_in[1];
    const float* cb3 = (const float*)d_in[2];
    const float* rw  = (const float*)d_in[3];
    const float* rb  = (const float*)d_in[4];
    const float* clw = (const float*)d_in[5];
    const float* clb = (const float*)d_in[6];
    float* out = (float*)d_out;

    char* p = (char*)d_ws;
    auto alloc = [&](size_t n) { char* r = p; p += (n + 255) & ~(size_t)255; return r; };
    float*  part   = (float*)alloc((size_t)CS * 512 * NPIX * 4);  // 20.5 MB
    float*  feat   = (float*)alloc((size_t)512 * NPIX * 4);       // 5.12 MB
    float*  regcls = (float*)alloc((size_t)54 * NPIX * 4);        // 0.54 MB
    float4* boxes  = (float4*)alloc((size_t)NANCH * 16);          // 0.36 MB
    unsigned long long* keys = (unsigned long long*)alloc((size_t)NKEY * 8);
    int*    rank   = (int*)alloc((size_t)NANCH * 4);
    float4* sboxes = (float4*)alloc((size_t)PRE * 16);
    unsigned long long* mask = (unsigned long long*)alloc((size_t)PRE * MW * 8); // 4.6 MB

    hipMemsetAsync(rank, 0, (size_t)NANCH * 4, stream);
    conv3x3_part  <<<dim3(32, 20, CS), 64, 0, stream>>>(x, cw3, part);
    reduce_leaky  <<<5000, 256, 0, stream>>>(part, cb3, feat);
    conv1x1_heads <<<dim3(40, 3), 256, 0, stream>>>(feat, rw, rb, clw, clb, regcls);
    decodeK       <<<88, 256, 0, stream>>>(regcls, boxes, keys);
    rankK         <<<dim3(88, 8), 256, 0, stream>>>(keys, rank);
    scatterK      <<<88, 256, 0, stream>>>(boxes, rank, sboxes);
    nmsMaskK      <<<dim3(375, 4), 256, 0, stream>>>(sboxes, mask);
    nmsScanOutK   <<<1, 64, 0, stream>>>(mask, sboxes, out);
}

// Round 6
// 699.182 us; speedup vs baseline: 2.9537x; 1.0499x over previous
//
#include <hip/hip_runtime.h>

// ---------------------------------------------------------------------------
// RPN forward, MI355X. Only batch element 7 contributes to the output.
// conv3x3 (cin-split-8 partials, 2px x 16oc register tile) -> reduce+leaky ->
// 1x1 heads (4-wave cin split) -> decode/score/key -> O(N^2) rank sort ->
// top-6000 -> NMS bitmask (reference's yy2=max bug replicated) ->
// word-serial single-wave scan with speculative row prefetch -> 300x4 boxes.
// Deterministic fp32 everywhere (no float atomics).
// ---------------------------------------------------------------------------

#define NPIX 2500      // 50*50
#define NANCH 22500    // 2500*9
#define NKEY 22528     // NANCH padded to 88*256 (sentinel tail)
#define PRE 6000
#define MASKW 94       // ceil(6000/64) usable words
#define MW 96          // storage stride in words
#define JCHUNK 1536    // j-chunk for mask kernel (24 words)
#define CS 8           // cin splits for conv3x3 (20 waves/CU occupancy)
#define CGRP 64        // cin per split
#define SPEC 12        // speculative row-prefetch slots in scan

// ---------------- conv 3x3 partials: 2 pixels x 16 oc per lane -------------
// grid (32 ocGroups, 20 pixel tiles, 8 cin groups), block 64 (1 wave).
// 5120 waves = 20/CU = 5/SIMD to hide the wave-uniform s_load weight stream.
__global__ __launch_bounds__(64) void conv3x3_part(
    const float* __restrict__ x,    // batch-7 base (512,50,50)
    const float* __restrict__ wt,   // (512,512,3,3)
    float* __restrict__ part)       // (CS,512,2500)
{
    const int lane = threadIdx.x;
    const int tile = blockIdx.y;                 // 0..19
    const int ocb  = blockIdx.x * 16;
    const int cing = blockIdx.z * CGRP;

    const int p0 = tile * 64 + lane;             // < 1280 always
    const int p1 = p0 + 1280;
    const bool act1 = (p1 < NPIX);
    const int p1c = act1 ? p1 : (NPIX - 1);

    int   soff[18];
    float mk[18];
    {
        const int hh0 = p0 / 50,  ww0 = p0 - hh0 * 50;
        const int hh1 = p1c / 50, ww1 = p1c - hh1 * 50;
        #pragma unroll
        for (int r = 0; r < 3; ++r) {
            #pragma unroll
            for (int c = 0; c < 3; ++c) {
                int gr = hh0 + r - 1, gc = ww0 + c - 1;
                bool ok = (gr >= 0) & (gr < 50) & (gc >= 0) & (gc < 50);
                soff[r * 3 + c] = ok ? (gr * 50 + gc) : 0;
                mk[r * 3 + c]   = ok ? 1.0f : 0.0f;
                gr = hh1 + r - 1; gc = ww1 + c - 1;
                ok = (gr >= 0) & (gr < 50) & (gc >= 0) & (gc < 50);
                soff[9 + r * 3 + c] = ok ? (gr * 50 + gc) : 0;
                mk[9 + r * 3 + c]   = ok ? 1.0f : 0.0f;
            }
        }
    }

    float acc0[16], acc1[16];
    #pragma unroll
    for (int o = 0; o < 16; ++o) { acc0[o] = 0.f; acc1[o] = 0.f; }

    for (int cin = 0; cin < CGRP; ++cin) {
        const float* xp = x + (size_t)(cing + cin) * NPIX;
        float v[18];
        #pragma unroll
        for (int k = 0; k < 18; ++k)
            v[k] = xp[soff[k]] * mk[k];
        const float* wbase = wt + ((size_t)ocb * 512 + (cing + cin)) * 9;
        #pragma unroll
        for (int o = 0; o < 16; ++o) {
            const float* w = wbase + (size_t)o * 4608;  // wave-uniform -> s_load
            #pragma unroll
            for (int t = 0; t < 9; ++t) {
                acc0[o] = fmaf(w[t], v[t],     acc0[o]);
                acc1[o] = fmaf(w[t], v[9 + t], acc1[o]);
            }
        }
    }

    float* dst = part + ((size_t)blockIdx.z * 512 + ocb) * NPIX;
    #pragma unroll
    for (int o = 0; o < 16; ++o) {
        dst[(size_t)o * NPIX + p0] = acc0[o];
        if (act1) dst[(size_t)o * NPIX + p1] = acc1[o];
    }
}

// ---------------- reduce partials + bias + leaky ---------------------------
__global__ __launch_bounds__(256) void reduce_leaky(
    const float* __restrict__ part, const float* __restrict__ bias,
    float* __restrict__ feat)
{
    const int i = blockIdx.x * 256 + threadIdx.x;
    if (i >= 512 * NPIX) return;
    const int oc = i / NPIX;
    float s = part[i];
    #pragma unroll
    for (int k = 1; k < CS; ++k)
        s += part[(size_t)k * 512 * NPIX + i];
    s += bias[oc];
    s = (s >= 0.f) ? s : 0.01f * s;
    feat[i] = s;
}

// ---------------- 1x1 heads: 4-wave cin split + LDS tree reduce ------------
__global__ __launch_bounds__(256) void conv1x1_heads(
    const float* __restrict__ feat,
    const float* __restrict__ rw, const float* __restrict__ rb,
    const float* __restrict__ cw, const float* __restrict__ cb,
    float* __restrict__ regcls)   // (54, 2500)
{
    __shared__ float sAcc[3][18][64];
    const int tid  = threadIdx.x;
    const int lane = tid & 63;
    const int wv   = tid >> 6;
    const int pix0 = blockIdx.x * 64 + lane;
    const bool act = (pix0 < NPIX);
    const int pix  = act ? pix0 : (NPIX - 1);
    const int chunk = blockIdx.y;
    const float* wb; const float* bb; int ocbase;
    if (chunk == 0)      { wb = rw;            bb = rb;      ocbase = 0;  }
    else if (chunk == 1) { wb = rw + 18 * 512; bb = rb + 18; ocbase = 18; }
    else                 { wb = cw;            bb = cb;      ocbase = 36; }

    float acc[18];
    #pragma unroll
    for (int k = 0; k < 18; ++k) acc[k] = 0.f;

    const int c0 = wv * 128;
    for (int cin = c0; cin < c0 + 128; ++cin) {
        const float v = feat[(size_t)cin * NPIX + pix];
        #pragma unroll
        for (int k = 0; k < 18; ++k)
            acc[k] = fmaf(wb[k * 512 + cin], v, acc[k]);
    }
    if (wv > 0) {
        #pragma unroll
        for (int k = 0; k < 18; ++k) sAcc[wv - 1][k][lane] = acc[k];
    }
    __syncthreads();
    if (wv == 0 && act) {
        #pragma unroll
        for (int k = 0; k < 18; ++k) {
            float s = acc[k];
            s += sAcc[0][k][lane];
            s += sAcc[1][k][lane];
            s += sAcc[2][k][lane];
            regcls[(size_t)(ocbase + k) * NPIX + pix] = s + bb[k];
        }
    }
}

// ---------------- decode: anchors, softmax score, sortable key -------------
__global__ __launch_bounds__(256) void decodeK(
    const float* __restrict__ regcls,
    float4* __restrict__ boxes,
    unsigned long long* __restrict__ keys)
{
    const int i = blockIdx.x * 256 + threadIdx.x;
    if (i >= NANCH) {
        if (i < NKEY) keys[i] = 0xFFFFFFFFFFFFFFFFull;  // sentinel: > all keys
        return;
    }
    const int pos = i / 9;
    const int a   = i - pos * 9;
    const int hh  = pos / 50;
    const int wwp = pos - hh * 50;
    const int r = a / 3, s = a - r * 3;

    const float base_s[3] = {128.f, 256.f, 512.f};
    const float sq [3] = {0.70710678118654752440f, 1.0f, 1.41421356237309504880f};
    const float sqi[3] = {1.41421356237309504880f, 1.0f, 0.70710678118654752440f};
    const float hs = base_s[s] * sq[r];
    const float ws = base_s[s] * sqi[r];
    const float cx = (float)(hh * 16 + 8);    // cx indexed by h (reference quirk)
    const float cy = (float)(wwp * 16 + 8);
    const float ax = cx - ws * 0.5f;
    const float ay = cy - hs * 0.5f;

    const float pr0 = regcls[(size_t)(a * 4 + 0) * NPIX + pos];
    const float pr1 = regcls[(size_t)(a * 4 + 1) * NPIX + pos];
    const float pr2 = regcls[(size_t)(a * 4 + 2) * NPIX + pos];
    const float pr3 = regcls[(size_t)(a * 4 + 3) * NPIX + pos];
    const float c0  = regcls[(size_t)(36 + a * 2 + 0) * NPIX + pos];
    const float c1  = regcls[(size_t)(36 + a * 2 + 1) * NPIX + pos];

    const float m  = fmaxf(c0, c1);
    const float e0 = expf(c0 - m);
    const float e1 = expf(c1 - m);
    const float score = e1 / (e0 + e1);

    const float t0 = pr0 + ax;
    const float t1 = pr1 + ay;
    const float hi = 799.0f;
    const float rx1 = fminf(fmaxf(t0, 0.f), hi);
    const float ry1 = fminf(fmaxf(t1, 0.f), hi);
    const float rx2 = fminf(fmaxf((t0 + pr2) + ws, 0.f), hi);
    const float ry2 = fminf(fmaxf((t1 + pr3) + hs, 0.f), hi);
    const float bw = pr2 + ws;
    const float bh = pr3 + hs;
    const bool valid = (bw >= 16.f) && (bh >= 16.f);
    const float sc = valid ? score : -__builtin_inff();

    unsigned u = __float_as_uint(sc);
    u = (u & 0x80000000u) ? ~u : (u | 0x80000000u);  // monotone ascending map
    const unsigned k32 = ~u;                          // descending score
    keys[i]  = ((unsigned long long)k32 << 32) | (unsigned)i;  // tie: asc index
    boxes[i] = make_float4(rx1, ry1, rx2, ry2);
}

// ---------------- O(N^2) rank (stable argsort position) --------------------
__global__ __launch_bounds__(256) void rankK(
    const unsigned long long* __restrict__ keys, int* __restrict__ rank)
{
    const int i = blockIdx.x * 256 + threadIdx.x;
    const unsigned long long my = (i < NANCH) ? keys[i] : 0ull;
    const unsigned long long* kj = keys + blockIdx.y * 2816;
    int cnt = 0;
    for (int t = 0; t < 2816; t += 8) {
        #pragma unroll
        for (int q = 0; q < 8; ++q)
            cnt += (kj[t + q] < my) ? 1 : 0;
    }
    if (i < NANCH) atomicAdd(&rank[i], cnt);
}

__global__ __launch_bounds__(256) void scatterK(
    const float4* __restrict__ boxes, const int* __restrict__ rank,
    float4* __restrict__ sboxes)
{
    const int i = blockIdx.x * 256 + threadIdx.x;
    if (i < NANCH) {
        const int r = rank[i];
        if (r < PRE) sboxes[r] = boxes[i];
    }
}

// ---------------- NMS suppression bitmask (reference bug replicated) -------
__global__ __launch_bounds__(256) void nmsMaskK(
    const float4* __restrict__ sb, unsigned long long* __restrict__ mask)
{
    __shared__ float sx1[JCHUNK], sy1[JCHUNK], sx2[JCHUNK], sy2[JCHUNK], sar[JCHUNK];
    const int tid = threadIdx.x;
    const int jbase = blockIdx.y * JCHUNK;
    for (int t = tid; t < JCHUNK; t += 256) {
        const int j = jbase + t;
        if (j < PRE) {
            const float4 b = sb[j];
            sx1[t] = b.x; sy1[t] = b.y; sx2[t] = b.z; sy2[t] = b.w;
            sar[t] = (b.z - b.x + 1.f) * (b.w - b.y + 1.f);
        } else {
            sx1[t] = 0.f; sy1[t] = 0.f; sx2[t] = -1.f; sy2[t] = 0.f; sar[t] = 0.f;
        }
    }
    __syncthreads();
    const int i = blockIdx.x * 16 + (tid >> 4);
    const float4 bi = sb[i];
    const float x1 = bi.x, y1 = bi.y, x2 = bi.z, y2 = bi.w;
    const float ar = (x2 - x1 + 1.f) * (y2 - y1 + 1.f);
    for (int w = (tid & 15); w < 24; w += 16) {
        unsigned long long bits = 0ull;
        const int l0 = w * 64;
        for (int u = 0; u < 64; ++u) {
            const int j = jbase + l0 + u;
            if (j > i && j < PRE) {
                const int l = l0 + u;
                const float xx1 = fmaxf(x1, sx1[l]);
                const float yy1 = fmaxf(y1, sy1[l]);
                const float xx2 = fminf(x2, sx2[l]);
                const float yy2 = fmaxf(y2, sy2[l]);        // reference bug: max
                const float wv = fmaxf(0.f, xx2 - xx1 + 1.f);
                const float hv = fmaxf(0.f, yy2 - yy1 + 1.f);
                const float inter = wv * hv;
                const float ov = inter / ((ar + sar[l]) - inter);  // precise div
                if (ov > 0.7f) bits |= (1ull << u);
            }
        }
        mask[(size_t)i * MW + blockIdx.y * 24 + w] = bits;
    }
}

// ---------------- word-serial NMS scan + output (single wave) --------------
__global__ __launch_bounds__(64) void nmsScanOutK(
    const unsigned long long* __restrict__ mask,
    const float4* __restrict__ sb,
    float* __restrict__ out)
{
    __shared__ int sKept[300];
    __shared__ unsigned long long sKeepW[MASKW];
    const int lane = threadIdx.x;

    unsigned long long rem0 = 0ull, rem1 = 0ull;   // lane l: words l, 64+l
    int cnt = 0;
    int done = 0;

    unsigned long long diag = mask[(size_t)lane * MW + 0];   // block 0 diag

    for (int g = 0; g < MASKW && !done; ++g) {
        unsigned long long diag_next = 0ull;
        if (g + 1 < MASKW) {
            const int r2 = (g + 1) * 64 + lane;
            if (r2 < PRE) diag_next = mask[(size_t)r2 * MW + (g + 1)];
        }
        unsigned long long cur;
        {
            unsigned lo, hi;
            if (g < 64) {
                lo = __builtin_amdgcn_readlane((unsigned)rem0, g);
                hi = __builtin_amdgcn_readlane((unsigned)(rem0 >> 32), g);
            } else {
                lo = __builtin_amdgcn_readlane((unsigned)rem1, g - 64);
                hi = __builtin_amdgcn_readlane((unsigned)(rem1 >> 32), g - 64);
            }
            cur = ((unsigned long long)hi << 32) | lo;
        }
        const unsigned long long valid =
            (g == MASKW - 1) ? 0x0000FFFFFFFFFFFFull : ~0ull;   // 48 tail bits

        // speculative parallel prefetch of candidate rows
        unsigned long long sp0[SPEC], sp1[SPEC];
        int sbit[SPEC];
        int ns = 0;
        {
            unsigned long long t = (~cur) & valid;
            while (t && ns < SPEC) {
                const int b = __builtin_ctzll(t); t &= t - 1;
                const unsigned long long* pr = mask + (size_t)(g * 64 + b) * MW;
                sp0[ns] = pr[lane];
                sp1[ns] = (lane < MASKW - 64) ? pr[64 + lane] : 0ull;
                sbit[ns] = b;
                ++ns;
            }
        }

        unsigned long long procd = 0ull;
        unsigned long long kb = 0ull;
        int slot = 0;

        for (;;) {                                   // serial, pure ALU + reg ORs
            const unsigned long long nd = (~cur) & valid & ~procd;
            if (!nd) break;
            const int b = __builtin_ctzll(nd);
            procd |= (1ull << b);
            if (lane == 0 && cnt < 300) sKept[cnt] = g * 64 + b;
            ++cnt;
            kb |= (1ull << b);
            if (cnt >= 300) { done = 1; break; }
            const unsigned dlo = __builtin_amdgcn_readlane((unsigned)diag, b);
            const unsigned dhi = __builtin_amdgcn_readlane((unsigned)(diag >> 32), b);
            cur |= ((unsigned long long)dhi << 32) | dlo;
            while (slot < ns && sbit[slot] < b) ++slot;
            if (slot < ns && sbit[slot] == b) {
                rem0 |= sp0[slot];
                rem1 |= sp1[slot];
                ++slot;
            } else {
                const unsigned long long* pr = mask + (size_t)(g * 64 + b) * MW;
                rem0 |= pr[lane];
                rem1 |= (lane < MASKW - 64) ? pr[64 + lane] : 0ull;
            }
        }
        if (lane == 0) sKeepW[g] = kb;
        diag = diag_next;
    }

    __syncthreads();                                 // publish sKeepW / sKept

    if (cnt < 300) {                                 // filler: unkept, asc index
        int c = cnt;
        for (int g = 0; g < MASKW && c < 300; ++g) {
            const unsigned long long valid =
                (g == MASKW - 1) ? 0x0000FFFFFFFFFFFFull : ~0ull;
            unsigned long long u = (~sKeepW[g]) & valid;
            while (u && c < 300) {
                const int b = __builtin_ctzll(u); u &= u - 1;
                if (lane == 0) sKept[c] = g * 64 + b;
                ++c;
            }
        }
    }
    __syncthreads();

    for (int s = lane; s < 300; s += 64) {
        const float4 b = sb[sKept[s]];
        out[s * 4 + 0] = b.x;
        out[s * 4 + 1] = b.y;
        out[s * 4 + 2] = b.z - b.x + 1.0f;
        out[s * 4 + 3] = b.w - b.y + 1.0f;
    }
}

// ---------------------------------------------------------------------------
extern "C" void kernel_launch(void* const* d_in, const int* in_sizes, int n_in,
                              void* d_out, int out_size, void* d_ws, size_t ws_size,
                              hipStream_t stream)
{
    (void)in_sizes; (void)n_in; (void)out_size; (void)ws_size;
    const float* x   = (const float*)d_in[0] + (size_t)7 * 512 * NPIX; // batch 7
    const float* cw3 = (const float*)d_in[1];
    const float* cb3 = (const float*)d_in[2];
    const float* rw  = (const float*)d_in[3];
    const float* rb  = (const float*)d_in[4];
    const float* clw = (const float*)d_in[5];
    const float* clb = (const float*)d_in[6];
    float* out = (float*)d_out;

    char* p = (char*)d_ws;
    auto alloc = [&](size_t n) { char* r = p; p += (n + 255) & ~(size_t)255; return r; };
    float*  part   = (float*)alloc((size_t)CS * 512 * NPIX * 4);  // 41 MB
    float*  feat   = (float*)alloc((size_t)512 * NPIX * 4);       // 5.12 MB
    float*  regcls = (float*)alloc((size_t)54 * NPIX * 4);        // 0.54 MB
    float4* boxes  = (float4*)alloc((size_t)NANCH * 16);          // 0.36 MB
    unsigned long long* keys = (unsigned long long*)alloc((size_t)NKEY * 8);
    int*    rank   = (int*)alloc((size_t)NANCH * 4);
    float4* sboxes = (float4*)alloc((size_t)PRE * 16);
    unsigned long long* mask = (unsigned long long*)alloc((size_t)PRE * MW * 8); // 4.6 MB

    hipMemsetAsync(rank, 0, (size_t)NANCH * 4, stream);
    conv3x3_part  <<<dim3(32, 20, CS), 64, 0, stream>>>(x, cw3, part);
    reduce_leaky  <<<5000, 256, 0, stream>>>(part, cb3, feat);
    conv1x1_heads <<<dim3(40, 3), 256, 0, stream>>>(feat, rw, rb, clw, clb, regcls);
    decodeK       <<<88, 256, 0, stream>>>(regcls, boxes, keys);
    rankK         <<<dim3(88, 8), 256, 0, stream>>>(keys, rank);
    scatterK      <<<88, 256, 0, stream>>>(boxes, rank, sboxes);
    nmsMaskK      <<<dim3(375, 4), 256, 0, stream>>>(sboxes, mask);
    nmsScanOutK   <<<1, 64, 0, stream>>>(mask, sboxes, out);
}